// Round 4
// baseline (363.602 us; speedup 1.0000x reference)
//
#include <hip/hip_runtime.h>
#include <math.h>

#define B 16
#define CIN 512
#define COUT 512
#define SDIM 512
#define H 64
#define W 64

typedef short s16x8 __attribute__((ext_vector_type(8)));
typedef float f32x4 __attribute__((ext_vector_type(4)));

__device__ __constant__ float LIN_SCALE  = 0.04419417382415922f;   // 1/sqrt(512)
__device__ __constant__ float CONV_SCALE = 0.014731391274719742f;  // 1/sqrt(512*9)

__device__ __forceinline__ ushort f2bf(float f) {
  unsigned u = __float_as_uint(f);
  return (ushort)((u + 0x7FFFu + ((u >> 16) & 1u)) >> 16);  // RNE
}

#define GLOAD16(g, l)                                           \
  __builtin_amdgcn_global_load_lds(                             \
      (const __attribute__((address_space(1))) unsigned*)(g),   \
      (__attribute__((address_space(3))) unsigned*)(l), 16, 0, 0)

// ---------------------------------------------------------------------------
// Kernel 1: s[b,ci] = style[b,:] . style_w[ci,:] * lin_scale + style_b[ci]
// ---------------------------------------------------------------------------
__global__ __launch_bounds__(512) void style_mod_kernel(
    const float* __restrict__ style, const float* __restrict__ style_w,
    const float* __restrict__ style_b, float* __restrict__ s,
    float* __restrict__ s2) {
  const int b = blockIdx.x;
  const int ci = threadIdx.x;
  __shared__ float st[SDIM];
  st[ci] = style[b * SDIM + ci];
  __syncthreads();

  const float4* wr = reinterpret_cast<const float4*>(style_w + (size_t)ci * SDIM);
  float acc = 0.f;
#pragma unroll 4
  for (int k = 0; k < SDIM / 4; ++k) {
    float4 wv = wr[k];
    acc += st[4 * k + 0] * wv.x + st[4 * k + 1] * wv.y +
           st[4 * k + 2] * wv.z + st[4 * k + 3] * wv.w;
  }
  float v = acc * LIN_SCALE + style_b[ci];
  s[b * CIN + ci] = v;
  s2[b * CIN + ci] = v * v;
}

// ---------------------------------------------------------------------------
// Kernel 2: wsq[co,ci] = sum_k weight[co,ci,k]^2
// ---------------------------------------------------------------------------
__global__ __launch_bounds__(256) void wsq_kernel(
    const float* __restrict__ weight, float* __restrict__ wsq) {
  const int i = blockIdx.x * blockDim.x + threadIdx.x;
  if (i >= COUT * CIN) return;
  const float* p = weight + (size_t)i * 9;
  float a = 0.f;
#pragma unroll
  for (int k = 0; k < 9; ++k) {
    float v = p[k];
    a += v * v;
  }
  wsq[i] = a;
}

// ---------------------------------------------------------------------------
// Kernel 3: outscale[b,co] = conv_scale * rsqrt(conv_scale^2 * sum + 1e-8)
// ---------------------------------------------------------------------------
__global__ __launch_bounds__(512) void dcoef_kernel(
    const float* __restrict__ s2, const float* __restrict__ wsq,
    float* __restrict__ outscale) {
  const int b = blockIdx.x;
  const int co = threadIdx.x;
  __shared__ float sh[CIN];
  sh[co] = s2[b * CIN + co];
  __syncthreads();

  const float4* wr = reinterpret_cast<const float4*>(wsq + (size_t)co * CIN);
  float acc = 0.f;
#pragma unroll 4
  for (int k = 0; k < CIN / 4; ++k) {
    float4 wv = wr[k];
    acc += sh[4 * k + 0] * wv.x + sh[4 * k + 1] * wv.y +
           sh[4 * k + 2] * wv.z + sh[4 * k + 3] * wv.w;
  }
  float d = rsqrtf(acc * CONV_SCALE * CONV_SCALE + 1e-8f);
  outscale[b * COUT + co] = d * CONV_SCALE;
}

// ---------------------------------------------------------------------------
// Kernel P1: pack weights -> wt[chunk][j][co][slot][8ci] bf16,
// slot = s ^ ((co>>1)&3)  (bank swizzle baked into global layout).
// Byte strides: chunk 294912, j 32768, co 64, slot 16.
// ---------------------------------------------------------------------------
__global__ __launch_bounds__(256) void pack_w_kernel(
    const float* __restrict__ w, ushort* __restrict__ wt) {
  const int t = blockIdx.x * 256 + threadIdx.x;  // 32768 threads
  const int s = t & 3;
  const int chunk = (t >> 2) & 15;
  const int co = t >> 6;
  const float4* wp =
      (const float4*)(w + ((size_t)co * 512 + chunk * 32 + s * 8) * 9);
  float wv[72];
#pragma unroll
  for (int i = 0; i < 18; ++i) {
    float4 v = wp[i];
    wv[4 * i + 0] = v.x; wv[4 * i + 1] = v.y;
    wv[4 * i + 2] = v.z; wv[4 * i + 3] = v.w;
  }
  const int sp = s ^ ((co >> 1) & 3);
  ushort* dst = wt + (size_t)chunk * 147456 + (size_t)co * 32 + sp * 8;
#pragma unroll
  for (int j = 0; j < 9; ++j) {
    s16x8 p;
#pragma unroll
    for (int i = 0; i < 8; ++i) p[i] = (short)f2bf(wv[i * 9 + j]);
    *(s16x8*)(dst + (size_t)j * 16384) = p;
  }
}

// ---------------------------------------------------------------------------
// Kernel P2: pack x -> xp[b][chunk][gr][c][slot][8ci] bf16, s folded in;
// slot = s ^ (((c+1)>>1)&3). Byte strides: (b,chunk) 262144, gr 4096, c 64.
// ---------------------------------------------------------------------------
__global__ __launch_bounds__(256) void pack_x_kernel(
    const float* __restrict__ x, const float* __restrict__ smod,
    ushort* __restrict__ xp) {
  __shared__ float xt[32][65];
  __shared__ float sm[32];
  const int tid = threadIdx.x;
  const int gr = blockIdx.x, chunk = blockIdx.y, b = blockIdx.z;
  if (tid < 32) sm[tid] = smod[b * 512 + chunk * 32 + tid];
  {
    const int ci = tid >> 3, cq = tid & 7;
    const float4* rp = (const float4*)(
        x + (((size_t)b * 512 + chunk * 32 + ci) * 64 + gr) * 64 + cq * 8);
    float4 a = rp[0], c2 = rp[1];
    float* row = &xt[ci][cq * 8];
    row[0] = a.x; row[1] = a.y; row[2] = a.z; row[3] = a.w;
    row[4] = c2.x; row[5] = c2.y; row[6] = c2.z; row[7] = c2.w;
  }
  __syncthreads();
  const int c = tid >> 2, s = tid & 3;
  s16x8 p;
#pragma unroll
  for (int i = 0; i < 8; ++i)
    p[i] = (short)f2bf(xt[s * 8 + i][c] * sm[s * 8 + i]);
  const int sp = s ^ (((c + 1) >> 1) & 3);
  *(s16x8*)(xp + ((size_t)(b * 16 + chunk) * 64 + gr) * 2048 + c * 32 + sp * 8) = p;
}

// ---------------------------------------------------------------------------
// Kernel 4 (new): dbuf-prefetch MFMA conv.
// 512 thr / 8 waves; tile 64 co x 8 rows x 64 px; wave wid owns row h0+wid.
// Dynamic LDS 158208 B: ws[2][9][64][32] @0, xs[2][10][66][32] @73728.
// Per chunk: one __syncthreads (drains vmcnt -> chunk-c data visible, syncs
// buffer reuse), then fire-and-forget STAGE of chunk c+1 into the other
// buffer (19 gload_lds16/wave-pair), then 72 swizzled ds_read_b128 +
// 144 mfma per wave. Chunk c+1's loads fly across compute(c).
// ---------------------------------------------------------------------------
#define WSBUF 36864
#define XSBUF 42240
#define XSOFF 73728

__global__ __launch_bounds__(512, 2) void conv_mfma3_kernel(
    const ushort* __restrict__ wt, const ushort* __restrict__ xp,
    const float* __restrict__ outscale, float* __restrict__ out) {
  extern __shared__ char smem[];

  const int tid = threadIdx.x;
  const int hb = blockIdx.x;  // 0..7
  const int cb = blockIdx.y;  // 0..7
  const int b  = blockIdx.z;  // 0..15
  const int h0 = hb * 8, co0 = cb * 64;
  const int lane = tid & 63, wid = tid >> 6;  // 8 waves
  const int l15 = lane & 15, l4 = lane >> 4;

  // zero both xs buffers (halo cols 0/65 + OOB rows rely on this)
  {
    s16x8* p = (s16x8*)(smem + XSOFF);
    for (int e = tid; e < (2 * XSBUF) / 16; e += 512) p[e] = (s16x8)0;
  }

  f32x4 acc[4][4];
#pragma unroll
  for (int mt = 0; mt < 4; ++mt)
#pragma unroll
    for (int nt = 0; nt < 4; ++nt) acc[mt][nt] = (f32x4)0.f;

  // swizzled loop-invariant read offsets (within a buffer)
  const int am = (l4 ^ ((l15 >> 1) & 3)) * 16;
  int aoff[4];
#pragma unroll
  for (int mt = 0; mt < 4; ++mt) aoff[mt] = (mt * 16 + l15) * 64 + am;
  int boff[12];
#pragma unroll
  for (int nt = 0; nt < 4; ++nt)
#pragma unroll
    for (int kw = 0; kw < 3; ++kw) {
      int col = nt * 16 + l15 + kw;
      boff[nt * 3 + kw] =
          wid * 4224 + col * 64 + ((l4 ^ ((col >> 1) & 3)) * 16);
    }

  const char* wsrc0 = (const char*)wt + cb * 4096 + lane * 16;
  const char* xsrc0 = (const char*)xp + (size_t)b * 4194304 + lane * 16;

  __syncthreads();  // zero visible before first stage

  // STAGE(chunk, buf): 76 gload16 instrs spread over 8 waves
  auto stage = [&](int chunk, int buf) {
    const char* wsrc = wsrc0 + (size_t)chunk * 294912;
    const char* xsrc = xsrc0 + (size_t)chunk * 262144;
    char* wdst = smem + buf * WSBUF + lane * 16;
    char* xdst = smem + XSOFF + buf * XSBUF + 64 + lane * 16;
    for (int e = wid; e < 76; e += 8) {
      if (e < 36) {
        int j = e >> 2, q = e & 3;
        GLOAD16(wsrc + j * 32768 + q * 1024, wdst + j * 4096 + q * 1024);
      } else {
        int r = (e - 36) >> 2, q = (e - 36) & 3;
        int gr = h0 - 1 + r;
        if ((unsigned)gr < 64u)
          GLOAD16(xsrc + (size_t)gr * 4096 + q * 1024,
                  xdst + r * 4224 + q * 1024);
      }
    }
  };

  auto compute = [&](int buf) {
    const char* wb = smem + buf * WSBUF;
    const char* xb = smem + XSOFF + buf * XSBUF;
#pragma unroll
    for (int kh = 0; kh < 3; ++kh) {
      const char* xrow = xb + kh * 4224;
#pragma unroll
      for (int kw = 0; kw < 3; ++kw) {
        const int j = kh * 3 + kw;
        const char* wj = wb + j * 4096;
        s16x8 af[4], bf[4];
#pragma unroll
        for (int mt = 0; mt < 4; ++mt)
          af[mt] = *(const s16x8*)(wj + aoff[mt]);
#pragma unroll
        for (int nt = 0; nt < 4; ++nt)
          bf[nt] = *(const s16x8*)(xrow + boff[nt * 3 + kw]);
#pragma unroll
        for (int mt = 0; mt < 4; ++mt)
#pragma unroll
          for (int nt = 0; nt < 4; ++nt)
            acc[mt][nt] = __builtin_amdgcn_mfma_f32_16x16x32_bf16(
                af[mt], bf[nt], acc[mt][nt], 0, 0, 0);
      }
    }
  };

  stage(0, 0);
  for (int c = 0; c < 16; c += 2) {
    __syncthreads();              // chunk c loads drained + buffer-reuse sync
    if (c + 1 < 16) stage(c + 1, 1);
    compute(0);
    __syncthreads();              // chunk c+1 drained
    if (c + 2 < 16) stage(c + 2, 0);
    compute(1);
  }

  // epilogue: D col(pixel)=lane&15, row(co)=(lane>>4)*4+reg
  const int h = h0 + wid;
#pragma unroll
  for (int mt = 0; mt < 4; ++mt) {
#pragma unroll
    for (int r = 0; r < 4; ++r) {
      const int co = co0 + mt * 16 + l4 * 4 + r;
      const float osc = outscale[b * COUT + co];
      float* orow = out + (((size_t)b * COUT + co) * H + h) * W;
#pragma unroll
      for (int nt = 0; nt < 4; ++nt)
        orow[nt * 16 + l15] = acc[mt][nt][r] * osc;
    }
  }
}

// ---------------------------------------------------------------------------
// Fallback conv (R3, proven): 2-phase, static LDS, 2 blocks/CU.
// ---------------------------------------------------------------------------
__global__ __launch_bounds__(256, 2) void conv_mfma2_kernel(
    const ushort* __restrict__ wt, const ushort* __restrict__ xp,
    const float* __restrict__ outscale, float* __restrict__ out) {
  __shared__ ushort ws[9][64][32];
  __shared__ ushort xs[6][66][32];

  const int tid = threadIdx.x;
  const int hb = blockIdx.x, cb = blockIdx.y, b = blockIdx.z;
  const int h0 = hb * 4, co0 = cb * 64;
  const int lane = tid & 63, wid = tid >> 6;
  const int l15 = lane & 15, l4 = lane >> 4;

  {
    s16x8* p = (s16x8*)&xs[0][0][0];
    for (int e = tid; e < 1584; e += 256) p[e] = (s16x8)0;
  }

  f32x4 acc[4][4];
#pragma unroll
  for (int mt = 0; mt < 4; ++mt)
#pragma unroll
    for (int nt = 0; nt < 4; ++nt) acc[mt][nt] = (f32x4)0.f;

  const int am = (l4 ^ ((l15 >> 1) & 3)) * 16;
  int aoff[4];
#pragma unroll
  for (int mt = 0; mt < 4; ++mt) aoff[mt] = (mt * 16 + l15) * 64 + am;
  int boff[12];
#pragma unroll
  for (int nt = 0; nt < 4; ++nt)
#pragma unroll
    for (int kw = 0; kw < 3; ++kw) {
      int col = nt * 16 + l15 + kw;
      boff[nt * 3 + kw] =
          wid * 4224 + col * 64 + ((l4 ^ ((col >> 1) & 3)) * 16);
    }

  const char* wsrc0 = (const char*)wt + cb * 4096 + wid * 1024 + lane * 16;
  const char* xsrc0 =
      (const char*)xp + (size_t)b * 4194304 + wid * 1024 + lane * 16;
  char* wdst = (char*)&ws[0][0][0] + wid * 1024 + lane * 16;
  char* xdst = (char*)&xs[0][0][0] + 64 + wid * 1024 + lane * 16;

  __syncthreads();

  for (int chunk = 0; chunk < 16; ++chunk) {
    const char* wsrc = wsrc0 + chunk * 294912;
    const char* xsrc = xsrc0 + chunk * 262144;
#pragma unroll
    for (int t = 0; t < 9; ++t)
      GLOAD16(wsrc + t * 32768, wdst + t * 4096);
#pragma unroll
    for (int t = 0; t < 6; ++t) {
      int gr = h0 - 1 + t;
      if ((unsigned)gr < 64u) GLOAD16(xsrc + gr * 4096, xdst + t * 4224);
    }
    __syncthreads();

#pragma unroll
    for (int kh = 0; kh < 3; ++kh) {
      const char* xrow = (const char*)&xs[0][0][0] + kh * 4224;
#pragma unroll
      for (int kw = 0; kw < 3; ++kw) {
        const int j = kh * 3 + kw;
        const char* wj = (const char*)&ws[0][0][0] + j * 4096;
        s16x8 af[4], bf[4];
#pragma unroll
        for (int mt = 0; mt < 4; ++mt)
          af[mt] = *(const s16x8*)(wj + aoff[mt]);
#pragma unroll
        for (int nt = 0; nt < 4; ++nt)
          bf[nt] = *(const s16x8*)(xrow + boff[nt * 3 + kw]);
#pragma unroll
        for (int mt = 0; mt < 4; ++mt)
#pragma unroll
          for (int nt = 0; nt < 4; ++nt)
            acc[mt][nt] = __builtin_amdgcn_mfma_f32_16x16x32_bf16(
                af[mt], bf[nt], acc[mt][nt], 0, 0, 0);
      }
    }
    __syncthreads();
  }

  const int h = h0 + wid;
#pragma unroll
  for (int mt = 0; mt < 4; ++mt) {
#pragma unroll
    for (int r = 0; r < 4; ++r) {
      const int co = co0 + mt * 16 + l4 * 4 + r;
      const float osc = outscale[b * COUT + co];
      float* orow = out + (((size_t)b * COUT + co) * H + h) * W;
#pragma unroll
      for (int nt = 0; nt < 4; ++nt)
        orow[nt * 16 + l15] = acc[mt][nt][r] * osc;
    }
  }
}

// ---------------------------------------------------------------------------
extern "C" void kernel_launch(void* const* d_in, const int* in_sizes, int n_in,
                              void* d_out, int out_size, void* d_ws,
                              size_t ws_size, hipStream_t stream) {
  const float* x = (const float*)d_in[0];
  const float* style = (const float*)d_in[1];
  const float* weight = (const float*)d_in[2];
  const float* style_w = (const float*)d_in[3];
  const float* style_b = (const float*)d_in[4];
  float* out = (float*)d_out;

  // workspace layout (bytes):
  //   0        s        (32768)
  //   32768    s2       (32768)
  //   65536    wsq      (1048576)
  //   1114112  outscale (32768)
  //   1146880  wt       (4718592)   packed bf16 weights
  //   5865472  xp       (67108864)  packed bf16 x (s folded)
  char* wsb = (char*)d_ws;
  float* s = (float*)(wsb + 0);
  float* s2 = (float*)(wsb + 32768);
  float* wsq = (float*)(wsb + 65536);
  float* outscale = (float*)(wsb + 1114112);
  ushort* wt = (ushort*)(wsb + 1146880);
  ushort* xp = (ushort*)(wsb + 5865472);
  const size_t NEED = 72974336;

  style_mod_kernel<<<B, 512, 0, stream>>>(style, style_w, style_b, s, s2);
  wsq_kernel<<<(COUT * CIN + 255) / 256, 256, 0, stream>>>(weight, wsq);
  dcoef_kernel<<<B, 512, 0, stream>>>(s2, wsq, outscale);

  pack_w_kernel<<<128, 256, 0, stream>>>(weight, wt);
  pack_x_kernel<<<dim3(64, 16, 16), 256, 0, stream>>>(x, s, xp);

  const int DLDS = 2 * WSBUF + 2 * XSBUF;  // 158208
  static_assert(2 * WSBUF + 2 * XSBUF == 158208, "lds layout");
  hipError_t attr_ok = hipFuncSetAttribute(
      reinterpret_cast<const void*>(conv_mfma3_kernel),
      hipFuncAttributeMaxDynamicSharedMemorySize, DLDS);

  if (attr_ok == hipSuccess && ws_size >= NEED) {
    conv_mfma3_kernel<<<dim3(8, 8, 16), 512, DLDS, stream>>>(wt, xp, outscale,
                                                             out);
  } else {
    conv_mfma2_kernel<<<dim3(16, 8, 16), 256, 0, stream>>>(wt, xp, outscale,
                                                           out);
  }
}

// Round 5
// 340.673 us; speedup vs baseline: 1.0673x; 1.0673x over previous
//
#include <hip/hip_runtime.h>
#include <math.h>

#define B 16
#define CIN 512
#define COUT 512
#define SDIM 512
#define H 64
#define W 64

typedef short s16x8 __attribute__((ext_vector_type(8)));
typedef float f32x4 __attribute__((ext_vector_type(4)));

__device__ __constant__ float LIN_SCALE  = 0.04419417382415922f;   // 1/sqrt(512)
__device__ __constant__ float CONV_SCALE = 0.014731391274719742f;  // 1/sqrt(512*9)

__device__ __forceinline__ ushort f2bf(float f) {
  unsigned u = __float_as_uint(f);
  return (ushort)((u + 0x7FFFu + ((u >> 16) & 1u)) >> 16);  // RNE
}

#define GLOAD16(g, l)                                           \
  __builtin_amdgcn_global_load_lds(                             \
      (const __attribute__((address_space(1))) unsigned*)(g),   \
      (__attribute__((address_space(3))) unsigned*)(l), 16, 0, 0)

// ---------------------------------------------------------------------------
// Kernel 1: s[b,ci] = style[b,:] . style_w[ci,:] * lin_scale + style_b[ci]
// ---------------------------------------------------------------------------
__global__ __launch_bounds__(512) void style_mod_kernel(
    const float* __restrict__ style, const float* __restrict__ style_w,
    const float* __restrict__ style_b, float* __restrict__ s,
    float* __restrict__ s2) {
  const int b = blockIdx.x;
  const int ci = threadIdx.x;
  __shared__ float st[SDIM];
  st[ci] = style[b * SDIM + ci];
  __syncthreads();

  const float4* wr = reinterpret_cast<const float4*>(style_w + (size_t)ci * SDIM);
  float acc = 0.f;
#pragma unroll 4
  for (int k = 0; k < SDIM / 4; ++k) {
    float4 wv = wr[k];
    acc += st[4 * k + 0] * wv.x + st[4 * k + 1] * wv.y +
           st[4 * k + 2] * wv.z + st[4 * k + 3] * wv.w;
  }
  float v = acc * LIN_SCALE + style_b[ci];
  s[b * CIN + ci] = v;
  s2[b * CIN + ci] = v * v;
}

// ---------------------------------------------------------------------------
// Kernel 2: wsq[co,ci] = sum_k weight[co,ci,k]^2
// ---------------------------------------------------------------------------
__global__ __launch_bounds__(256) void wsq_kernel(
    const float* __restrict__ weight, float* __restrict__ wsq) {
  const int i = blockIdx.x * blockDim.x + threadIdx.x;
  if (i >= COUT * CIN) return;
  const float* p = weight + (size_t)i * 9;
  float a = 0.f;
#pragma unroll
  for (int k = 0; k < 9; ++k) {
    float v = p[k];
    a += v * v;
  }
  wsq[i] = a;
}

// ---------------------------------------------------------------------------
// Kernel 3: outscale[b,co] = conv_scale * rsqrt(conv_scale^2 * sum + 1e-8)
// ---------------------------------------------------------------------------
__global__ __launch_bounds__(512) void dcoef_kernel(
    const float* __restrict__ s2, const float* __restrict__ wsq,
    float* __restrict__ outscale) {
  const int b = blockIdx.x;
  const int co = threadIdx.x;
  __shared__ float sh[CIN];
  sh[co] = s2[b * CIN + co];
  __syncthreads();

  const float4* wr = reinterpret_cast<const float4*>(wsq + (size_t)co * CIN);
  float acc = 0.f;
#pragma unroll 4
  for (int k = 0; k < CIN / 4; ++k) {
    float4 wv = wr[k];
    acc += sh[4 * k + 0] * wv.x + sh[4 * k + 1] * wv.y +
           sh[4 * k + 2] * wv.z + sh[4 * k + 3] * wv.w;
  }
  float d = rsqrtf(acc * CONV_SCALE * CONV_SCALE + 1e-8f);
  outscale[b * COUT + co] = d * CONV_SCALE;
}

// ---------------------------------------------------------------------------
// Kernel P1: pack weights -> wt[chunk][j][co][slot][8ci] bf16,
// slot = s ^ ((co>>1)&3)  (bank swizzle baked into global layout).
// Byte strides: chunk 294912, j 32768, co 64, slot 16.
// ---------------------------------------------------------------------------
__global__ __launch_bounds__(256) void pack_w_kernel(
    const float* __restrict__ w, ushort* __restrict__ wt) {
  const int t = blockIdx.x * 256 + threadIdx.x;  // 32768 threads
  const int s = t & 3;
  const int chunk = (t >> 2) & 15;
  const int co = t >> 6;
  const float4* wp =
      (const float4*)(w + ((size_t)co * 512 + chunk * 32 + s * 8) * 9);
  float wv[72];
#pragma unroll
  for (int i = 0; i < 18; ++i) {
    float4 v = wp[i];
    wv[4 * i + 0] = v.x; wv[4 * i + 1] = v.y;
    wv[4 * i + 2] = v.z; wv[4 * i + 3] = v.w;
  }
  const int sp = s ^ ((co >> 1) & 3);
  ushort* dst = wt + (size_t)chunk * 147456 + (size_t)co * 32 + sp * 8;
#pragma unroll
  for (int j = 0; j < 9; ++j) {
    s16x8 p;
#pragma unroll
    for (int i = 0; i < 8; ++i) p[i] = (short)f2bf(wv[i * 9 + j]);
    *(s16x8*)(dst + (size_t)j * 16384) = p;
  }
}

// ---------------------------------------------------------------------------
// Kernel P2: pack x -> xp[b][chunk][gr][c][slot][8ci] bf16, s folded in;
// slot = s ^ (((c+1)>>1)&3). Byte strides: (b,chunk) 262144, gr 4096, c 64.
// ---------------------------------------------------------------------------
__global__ __launch_bounds__(256) void pack_x_kernel(
    const float* __restrict__ x, const float* __restrict__ smod,
    ushort* __restrict__ xp) {
  __shared__ float xt[32][65];
  __shared__ float sm[32];
  const int tid = threadIdx.x;
  const int gr = blockIdx.x, chunk = blockIdx.y, b = blockIdx.z;
  if (tid < 32) sm[tid] = smod[b * 512 + chunk * 32 + tid];
  {
    const int ci = tid >> 3, cq = tid & 7;
    const float4* rp = (const float4*)(
        x + (((size_t)b * 512 + chunk * 32 + ci) * 64 + gr) * 64 + cq * 8);
    float4 a = rp[0], c2 = rp[1];
    float* row = &xt[ci][cq * 8];
    row[0] = a.x; row[1] = a.y; row[2] = a.z; row[3] = a.w;
    row[4] = c2.x; row[5] = c2.y; row[6] = c2.z; row[7] = c2.w;
  }
  __syncthreads();
  const int c = tid >> 2, s = tid & 3;
  s16x8 p;
#pragma unroll
  for (int i = 0; i < 8; ++i)
    p[i] = (short)f2bf(xt[s * 8 + i][c] * sm[s * 8 + i]);
  const int sp = s ^ (((c + 1) >> 1) & 3);
  *(s16x8*)(xp + ((size_t)(b * 16 + chunk) * 64 + gr) * 2048 + c * 32 + sp * 8) = p;
}

// ---------------------------------------------------------------------------
// Kernel 4: 2-rows-per-wave MFMA conv (R3 structure, better read:MFMA ratio).
// 256 thr / 4 waves; tile 64 co x 8 rows x 64 px; wave wid owns rows
// h0+2*wid, h0+2*wid+1. Per tap: 4 A-reads + 8 B-reads -> 32 mfma
// (108 ds_read_b128 / 288 mfma per chunk per wave => MFMA-bound).
// Dynamic LDS 79104 B: ws[9][64][32] @0, xs[10][66][32] @36864.
// 2 blocks/CU -> inter-block overlap hides barrier drains (R4 lesson).
// ---------------------------------------------------------------------------
#define XS4OFF 36864
#define DLDS4 79104

__global__ __launch_bounds__(256, 2) void conv_mfma4_kernel(
    const ushort* __restrict__ wt, const ushort* __restrict__ xp,
    const float* __restrict__ outscale, float* __restrict__ out) {
  extern __shared__ char smem[];

  const int tid = threadIdx.x;
  const int hb = blockIdx.x;  // 0..7 (8 rows per block)
  const int cb = blockIdx.y;  // 0..7
  const int b  = blockIdx.z;  // 0..15
  const int h0 = hb * 8, co0 = cb * 64;
  const int lane = tid & 63, wid = tid >> 6;  // 4 waves
  const int l15 = lane & 15, l4 = lane >> 4;

  // zero xs buffer once: halo cols 0/65 + OOB edge rows stay zero all chunks
  {
    s16x8* p = (s16x8*)(smem + XS4OFF);
    for (int e = tid; e < 2640; e += 256) p[e] = (s16x8)0;
  }

  f32x4 acc[2][4][4];
#pragma unroll
  for (int rr = 0; rr < 2; ++rr)
#pragma unroll
    for (int mt = 0; mt < 4; ++mt)
#pragma unroll
      for (int nt = 0; nt < 4; ++nt) acc[rr][mt][nt] = (f32x4)0.f;

  // swizzled loop-invariant read offsets
  const int am = (l4 ^ ((l15 >> 1) & 3)) * 16;
  int aoff[4];
#pragma unroll
  for (int mt = 0; mt < 4; ++mt) aoff[mt] = (mt * 16 + l15) * 64 + am;
  int bcol[12];
#pragma unroll
  for (int nt = 0; nt < 4; ++nt)
#pragma unroll
    for (int kw = 0; kw < 3; ++kw) {
      int col = nt * 16 + l15 + kw;
      bcol[nt * 3 + kw] = col * 64 + ((l4 ^ ((col >> 1) & 3)) * 16);
    }

  const char* wsrc0 = (const char*)wt + cb * 4096 + tid * 16;
  const char* xsrc0 = (const char*)xp + (size_t)b * 4194304 + tid * 16;
  char* wdst = smem + tid * 16;
  char* xdst = smem + XS4OFF + 64 + tid * 16;
  const char* wb = smem;
  const char* xb = smem + XS4OFF + 2 * wid * 4224;  // wave's top xs row

  __syncthreads();  // zero visible

  for (int chunk = 0; chunk < 16; ++chunk) {
    const char* wsrc = wsrc0 + (size_t)chunk * 294912;
    const char* xsrc = xsrc0 + (size_t)chunk * 262144;
#pragma unroll
    for (int t = 0; t < 9; ++t)
      GLOAD16(wsrc + t * 32768, wdst + t * 4096);
#pragma unroll
    for (int t = 0; t < 10; ++t) {
      int gr = h0 - 1 + t;
      if ((unsigned)gr < 64u)
        GLOAD16(xsrc + (size_t)gr * 4096, xdst + t * 4224);
    }
    __syncthreads();  // staged data visible

#pragma unroll
    for (int kh = 0; kh < 3; ++kh) {
#pragma unroll
      for (int kw = 0; kw < 3; ++kw) {
        const int j = kh * 3 + kw;
        const char* wj = wb + j * 4096;
        s16x8 af[4], bf[2][4];
#pragma unroll
        for (int mt = 0; mt < 4; ++mt)
          af[mt] = *(const s16x8*)(wj + aoff[mt]);
#pragma unroll
        for (int rr = 0; rr < 2; ++rr)
#pragma unroll
          for (int nt = 0; nt < 4; ++nt)
            bf[rr][nt] =
                *(const s16x8*)(xb + (rr + kh) * 4224 + bcol[nt * 3 + kw]);
#pragma unroll
        for (int rr = 0; rr < 2; ++rr)
#pragma unroll
          for (int mt = 0; mt < 4; ++mt)
#pragma unroll
            for (int nt = 0; nt < 4; ++nt)
              acc[rr][mt][nt] = __builtin_amdgcn_mfma_f32_16x16x32_bf16(
                  af[mt], bf[rr][nt], acc[rr][mt][nt], 0, 0, 0);
      }
    }
    __syncthreads();  // protect LDS before next chunk's staging
  }

  // epilogue: D col(pixel)=lane&15, row(co)=(lane>>4)*4+reg
#pragma unroll
  for (int rr = 0; rr < 2; ++rr) {
    const int h = h0 + 2 * wid + rr;
#pragma unroll
    for (int mt = 0; mt < 4; ++mt) {
#pragma unroll
      for (int r = 0; r < 4; ++r) {
        const int co = co0 + mt * 16 + l4 * 4 + r;
        const float osc = outscale[b * COUT + co];
        float* orow = out + (((size_t)b * COUT + co) * H + h) * W;
#pragma unroll
        for (int nt = 0; nt < 4; ++nt)
          orow[nt * 16 + l15] = acc[rr][mt][nt][r] * osc;
      }
    }
  }
}

// ---------------------------------------------------------------------------
// Fallback conv (R3, proven): 2-phase, static LDS, 2 blocks/CU, 1 row/wave.
// ---------------------------------------------------------------------------
__global__ __launch_bounds__(256, 2) void conv_mfma2_kernel(
    const ushort* __restrict__ wt, const ushort* __restrict__ xp,
    const float* __restrict__ outscale, float* __restrict__ out) {
  __shared__ ushort ws[9][64][32];
  __shared__ ushort xs[6][66][32];

  const int tid = threadIdx.x;
  const int hb = blockIdx.x, cb = blockIdx.y, b = blockIdx.z;
  const int h0 = hb * 4, co0 = cb * 64;
  const int lane = tid & 63, wid = tid >> 6;
  const int l15 = lane & 15, l4 = lane >> 4;

  {
    s16x8* p = (s16x8*)&xs[0][0][0];
    for (int e = tid; e < 1584; e += 256) p[e] = (s16x8)0;
  }

  f32x4 acc[4][4];
#pragma unroll
  for (int mt = 0; mt < 4; ++mt)
#pragma unroll
    for (int nt = 0; nt < 4; ++nt) acc[mt][nt] = (f32x4)0.f;

  const int am = (l4 ^ ((l15 >> 1) & 3)) * 16;
  int aoff[4];
#pragma unroll
  for (int mt = 0; mt < 4; ++mt) aoff[mt] = (mt * 16 + l15) * 64 + am;
  int boff[12];
#pragma unroll
  for (int nt = 0; nt < 4; ++nt)
#pragma unroll
    for (int kw = 0; kw < 3; ++kw) {
      int col = nt * 16 + l15 + kw;
      boff[nt * 3 + kw] =
          wid * 4224 + col * 64 + ((l4 ^ ((col >> 1) & 3)) * 16);
    }

  const char* wsrc0 = (const char*)wt + cb * 4096 + wid * 1024 + lane * 16;
  const char* xsrc0 =
      (const char*)xp + (size_t)b * 4194304 + wid * 1024 + lane * 16;
  char* wdst = (char*)&ws[0][0][0] + wid * 1024 + lane * 16;
  char* xdst = (char*)&xs[0][0][0] + 64 + wid * 1024 + lane * 16;

  __syncthreads();

  for (int chunk = 0; chunk < 16; ++chunk) {
    const char* wsrc = wsrc0 + chunk * 294912;
    const char* xsrc = xsrc0 + chunk * 262144;
#pragma unroll
    for (int t = 0; t < 9; ++t)
      GLOAD16(wsrc + t * 32768, wdst + t * 4096);
#pragma unroll
    for (int t = 0; t < 6; ++t) {
      int gr = h0 - 1 + t;
      if ((unsigned)gr < 64u) GLOAD16(xsrc + gr * 4096, xdst + t * 4224);
    }
    __syncthreads();

#pragma unroll
    for (int kh = 0; kh < 3; ++kh) {
      const char* xrow = (const char*)&xs[0][0][0] + kh * 4224;
#pragma unroll
      for (int kw = 0; kw < 3; ++kw) {
        const int j = kh * 3 + kw;
        const char* wj = (const char*)&ws[0][0][0] + j * 4096;
        s16x8 af[4], bf[4];
#pragma unroll
        for (int mt = 0; mt < 4; ++mt)
          af[mt] = *(const s16x8*)(wj + aoff[mt]);
#pragma unroll
        for (int nt = 0; nt < 4; ++nt)
          bf[nt] = *(const s16x8*)(xrow + boff[nt * 3 + kw]);
#pragma unroll
        for (int mt = 0; mt < 4; ++mt)
#pragma unroll
          for (int nt = 0; nt < 4; ++nt)
            acc[mt][nt] = __builtin_amdgcn_mfma_f32_16x16x32_bf16(
                af[mt], bf[nt], acc[mt][nt], 0, 0, 0);
      }
    }
    __syncthreads();
  }

  const int h = h0 + wid;
#pragma unroll
  for (int mt = 0; mt < 4; ++mt) {
#pragma unroll
    for (int r = 0; r < 4; ++r) {
      const int co = co0 + mt * 16 + l4 * 4 + r;
      const float osc = outscale[b * COUT + co];
      float* orow = out + (((size_t)b * COUT + co) * H + h) * W;
#pragma unroll
      for (int nt = 0; nt < 4; ++nt)
        orow[nt * 16 + l15] = acc[mt][nt][r] * osc;
    }
  }
}

// ---------------------------------------------------------------------------
extern "C" void kernel_launch(void* const* d_in, const int* in_sizes, int n_in,
                              void* d_out, int out_size, void* d_ws,
                              size_t ws_size, hipStream_t stream) {
  const float* x = (const float*)d_in[0];
  const float* style = (const float*)d_in[1];
  const float* weight = (const float*)d_in[2];
  const float* style_w = (const float*)d_in[3];
  const float* style_b = (const float*)d_in[4];
  float* out = (float*)d_out;

  // workspace layout (bytes):
  //   0        s        (32768)
  //   32768    s2       (32768)
  //   65536    wsq      (1048576)
  //   1114112  outscale (32768)
  //   1146880  wt       (4718592)   packed bf16 weights
  //   5865472  xp       (67108864)  packed bf16 x (s folded)
  char* wsb = (char*)d_ws;
  float* s = (float*)(wsb + 0);
  float* s2 = (float*)(wsb + 32768);
  float* wsq = (float*)(wsb + 65536);
  float* outscale = (float*)(wsb + 1114112);
  ushort* wt = (ushort*)(wsb + 1146880);
  ushort* xp = (ushort*)(wsb + 5865472);
  const size_t NEED = 72974336;

  style_mod_kernel<<<B, 512, 0, stream>>>(style, style_w, style_b, s, s2);
  wsq_kernel<<<(COUT * CIN + 255) / 256, 256, 0, stream>>>(weight, wsq);
  dcoef_kernel<<<B, 512, 0, stream>>>(s2, wsq, outscale);

  pack_w_kernel<<<128, 256, 0, stream>>>(weight, wt);
  pack_x_kernel<<<dim3(64, 16, 16), 256, 0, stream>>>(x, s, xp);

  hipError_t attr_ok = hipFuncSetAttribute(
      reinterpret_cast<const void*>(conv_mfma4_kernel),
      hipFuncAttributeMaxDynamicSharedMemorySize, DLDS4);

  if (attr_ok == hipSuccess && ws_size >= NEED) {
    conv_mfma4_kernel<<<dim3(8, 8, 16), 256, DLDS4, stream>>>(wt, xp, outscale,
                                                              out);
  } else {
    conv_mfma2_kernel<<<dim3(16, 8, 16), 256, 0, stream>>>(wt, xp, outscale,
                                                           out);
  }
}